// Round 4
// baseline (292.051 us; speedup 1.0000x reference)
//
#include <hip/hip_runtime.h>
#include <hip/hip_bf16.h>
#include <stdint.h>

// CrossAttention: B=8, C=256, H=W=64 (N=4096), CR=64.
// Pipeline:
//   wprep:     W (f32) -> Wb bf16 [576][256] (rows 0-63 Wq*log2e, 64-127 Wk, 128-383 Wv)
//   transpose: gui -> inT [B][N][256] bf16 ; projK, projV ; transpose src -> inT ; projQ
//   attn:      flash, QBLK=64, KVBLK=64; K & V reg-streamed from global (L2),
//              LDS only for P (XOR-swizzled) + scales + epilogue transpose.
// Scratch: Qb/Kb/Vb in d_ws (24 MB); inT (16 MB) + Wb (288 KB) inside d_out.

#define B_ 8
#define C_ 256
#define N_ 4096
#define CR_ 64

typedef unsigned short u16;
typedef __attribute__((ext_vector_type(8))) __bf16 bf16x8;
typedef __attribute__((ext_vector_type(4))) float f32x4;

__device__ __forceinline__ u16 f2bf(float f) {
  union { float f; unsigned int u; } v; v.f = f;
  unsigned int r = (v.u + 0x7fffu + ((v.u >> 16) & 1u)) >> 16;
  return (u16)r;
}
__device__ __forceinline__ unsigned int cvtpk(float a, float b) {
  unsigned int r;
  asm("v_cvt_pk_bf16_f32 %0, %1, %2" : "=v"(r) : "v"(a), "v"(b));
  return r;
}

// ---------------- Weight prep: f32 -> bf16, Q rows scaled by log2(e) --------
__global__ __launch_bounds__(256) void wprep_kernel(
    const float* __restrict__ Wq, const float* __restrict__ Wk,
    const float* __restrict__ Wv, u16* __restrict__ Wb)
{
  const int i = (blockIdx.x * 256 + threadIdx.x) * 4;  // 147456 elems total
  const int row = i >> 8;
  float4 v;
  float s = 1.0f;
  if (row < 64)       { v = *(const float4*)(Wq + i); s = 1.44269504f; }
  else if (row < 128) { v = *(const float4*)(Wk + i - 64 * 256); }
  else                { v = *(const float4*)(Wv + i - 128 * 256); }
  u16* o = Wb + i;
  o[0] = f2bf(v.x * s); o[1] = f2bf(v.y * s);
  o[2] = f2bf(v.z * s); o[3] = f2bf(v.w * s);
}

// ---------------- Transpose [C][N] f32 -> [N][C] bf16 ----------------------
// grid (64 px-tiles, 4 ch-tiles, B), 256 thr; tile 64px x 64ch via LDS.
__global__ __launch_bounds__(256) void transpose_kernel(
    const float* __restrict__ in, u16* __restrict__ outT)
{
  __shared__ u16 Tl[64 * 66];
  const int t = threadIdx.x;
  const int px0 = blockIdx.x * 64, ch0 = blockIdx.y * 64, b = blockIdx.z;
  const float* ip = in + ((size_t)(b * C_ + ch0)) * N_ + px0;
  const int cx = t >> 4, p4 = (t & 15) * 4;
#pragma unroll
  for (int p = 0; p < 4; ++p) {
    const int ch = cx + p * 16;
    float4 v = *(const float4*)(ip + (size_t)ch * N_ + p4);
    Tl[(p4 + 0) * 66 + ch] = f2bf(v.x);
    Tl[(p4 + 1) * 66 + ch] = f2bf(v.y);
    Tl[(p4 + 2) * 66 + ch] = f2bf(v.z);
    Tl[(p4 + 3) * 66 + ch] = f2bf(v.w);
  }
  __syncthreads();
  const int row = t >> 3, seg = t & 7;
  u16* op = outT + ((size_t)(b * N_) + px0) * C_ + ch0 + seg * 8;
#pragma unroll
  for (int p = 0; p < 2; ++p) {
    const int r2 = row + p * 32;
    *(uint4*)(op + (size_t)r2 * C_) = *(const uint4*)(&Tl[r2 * 66 + seg * 8]);
  }
}

// ---------------- Q/K projection (MFMA): M=64, K=256 -----------------------
// grid (32 px-blocks, B), 128 thr = 2 waves; wave tile = 64 px x 64 ch.
__global__ __launch_bounds__(128) void projqk_kernel(
    const u16* __restrict__ inT, const u16* __restrict__ W64, u16* __restrict__ dst)
{
  __shared__ u16 Tl[2 * 64 * 66];
  const int t = threadIdx.x, lane = t & 63, wave = t >> 6;
  const int lg = lane >> 4, lm = lane & 15;
  const int b = blockIdx.y;
  const int px0 = blockIdx.x * 128 + wave * 64;
  const u16* ib = inT + ((size_t)(b * N_) + px0) * C_;

  f32x4 acc[4][4];
  const f32x4 z4 = {0.f, 0.f, 0.f, 0.f};
#pragma unroll
  for (int i = 0; i < 4; ++i)
#pragma unroll
    for (int j = 0; j < 4; ++j) acc[i][j] = z4;

  for (int ks = 0; ks < 8; ++ks) {
    bf16x8 wf[4], pf[4];
#pragma unroll
    for (int mi = 0; mi < 4; ++mi)
      wf[mi] = *(const bf16x8*)(W64 + (mi * 16 + lm) * C_ + ks * 32 + lg * 8);
#pragma unroll
    for (int ni = 0; ni < 4; ++ni)
      pf[ni] = *(const bf16x8*)(ib + (size_t)(ni * 16 + lm) * C_ + ks * 32 + lg * 8);
#pragma unroll
    for (int mi = 0; mi < 4; ++mi)
#pragma unroll
      for (int ni = 0; ni < 4; ++ni)
        acc[mi][ni] = __builtin_amdgcn_mfma_f32_16x16x32_bf16(wf[mi], pf[ni], acc[mi][ni], 0, 0, 0);
  }

  // transpose D[ch][px] -> Tl[px][ch] (u32 pair-packed), then coalesced rows out
  u16* tw = Tl + wave * 4224;
#pragma unroll
  for (int mi = 0; mi < 4; ++mi)
#pragma unroll
    for (int ni = 0; ni < 4; ++ni)
#pragma unroll
      for (int rp = 0; rp < 2; ++rp)
        *(unsigned int*)&tw[(ni * 16 + lm) * 66 + mi * 16 + lg * 4 + rp * 2] =
            cvtpk(acc[mi][ni][rp * 2], acc[mi][ni][rp * 2 + 1]);

  const int row = lane >> 3, seg = lane & 7;
  u16* op = dst + ((size_t)(b * N_) + px0) * CR_ + seg * 8;
#pragma unroll
  for (int i = 0; i < 8; ++i) {
    const int r2 = row + i * 8;
    *(uint4*)(op + (size_t)r2 * CR_) = *(const uint4*)(&tw[r2 * 66 + seg * 8]);
  }
}

// ---------------- V projection (MFMA): M=128/block, K=256 ------------------
// grid (32 px-blocks, B, 2 ch-halves), 128 thr = 2 waves; wave = 64 ch, 2 px-groups.
__global__ __launch_bounds__(128) void projv_kernel(
    const u16* __restrict__ inT, const u16* __restrict__ Wv256,
    const float* __restrict__ bv, u16* __restrict__ Vb)
{
  const int t = threadIdx.x, lane = t & 63, wave = t >> 6;
  const int lg = lane >> 4, lm = lane & 15;
  const int b = blockIdx.y;
  const int px0 = blockIdx.x * 128;
  const int chb = blockIdx.z * 128 + wave * 64;
  const u16* ib = inT + ((size_t)(b * N_) + px0) * C_;
  const u16* wb = Wv256 + (size_t)chb * C_;

  f32x4 bq[4];
#pragma unroll
  for (int mi = 0; mi < 4; ++mi)
    bq[mi] = *(const f32x4*)(bv + chb + mi * 16 + lg * 4);

  const f32x4 z4 = {0.f, 0.f, 0.f, 0.f};
  for (int pg = 0; pg < 2; ++pg) {
    f32x4 acc[4][4];
#pragma unroll
    for (int i = 0; i < 4; ++i)
#pragma unroll
      for (int j = 0; j < 4; ++j) acc[i][j] = z4;
    for (int ks = 0; ks < 8; ++ks) {
      bf16x8 wf[4], pf[4];
#pragma unroll
      for (int mi = 0; mi < 4; ++mi)
        wf[mi] = *(const bf16x8*)(wb + (mi * 16 + lm) * C_ + ks * 32 + lg * 8);
#pragma unroll
      for (int ni = 0; ni < 4; ++ni)
        pf[ni] = *(const bf16x8*)(ib + (size_t)(pg * 64 + ni * 16 + lm) * C_ + ks * 32 + lg * 8);
#pragma unroll
      for (int mi = 0; mi < 4; ++mi)
#pragma unroll
        for (int ni = 0; ni < 4; ++ni)
          acc[mi][ni] = __builtin_amdgcn_mfma_f32_16x16x32_bf16(wf[mi], pf[ni], acc[mi][ni], 0, 0, 0);
    }
#pragma unroll
    for (int mi = 0; mi < 4; ++mi)
#pragma unroll
      for (int ni = 0; ni < 4; ++ni)
#pragma unroll
        for (int r = 0; r < 4; ++r)
          Vb[((size_t)(b * C_) + chb + mi * 16 + lg * 4 + r) * N_ +
             px0 + pg * 64 + ni * 16 + lm] = f2bf(acc[mi][ni][r] + bq[mi][r]);
  }
}

// ---------------- Flash attention kernel ----------------
// LDS: P [64 q][128 B] XOR-swizzled at 0 (8192 B); SC f32[64] @33792; FL f32[4] @34048.
// Epilogue: per-wave [64 q][33] f32 tiles at 0..33792 (P dead by then).
#define SCO 33792
#define FLO 34048

__global__ __launch_bounds__(256, 2) void attn_kernel(
    const u16* __restrict__ Qb, const u16* __restrict__ Kb, const u16* __restrict__ Vb,
    const float* __restrict__ source, const float* __restrict__ gamma,
    float* __restrict__ out)
{
  __shared__ uint4 smem4[2132];  // 34112 B
  char* smem = (char*)smem4;

  const int t = threadIdx.x;
  const int lane = t & 63;
  const int wave = t >> 6;
  const int lg = lane >> 4;
  const int lm = lane & 15;
  const int b = blockIdx.y;
  const int q0 = blockIdx.x * 64;
  const int sw = lm & 7;

  bf16x8 aq[2];
  {
    const u16* qp = Qb + ((size_t)(b * N_ + q0 + wave * 16 + lm)) * CR_ + lg * 8;
    aq[0] = *reinterpret_cast<const bf16x8*>(qp);
    aq[1] = *reinterpret_cast<const bf16x8*>(qp + 32);
  }

  const u16* KbT = Kb + (size_t)b * N_ * CR_;
  const u16* VbT = Vb + (size_t)b * C_ * N_;

  f32x4 accv[4][4];
  const f32x4 zero4 = {0.f, 0.f, 0.f, 0.f};
#pragma unroll
  for (int i = 0; i < 4; ++i)
#pragma unroll
    for (int j = 0; j < 4; ++j) accv[i][j] = zero4;
  float mrow = -1e30f, lrow = 0.f;

  bf16x8 kA[8], kB[8];

#define LOADK(KREG, KTILE) do {                                              \
    const u16* kb_ = KbT + (size_t)(KTILE) * (64 * CR_);                     \
    _Pragma("unroll")                                                        \
    for (int f = 0; f < 8; ++f)                                              \
      KREG[f] = *reinterpret_cast<const bf16x8*>(                            \
          kb_ + ((f >> 1) * 16 + lm) * CR_ + (f & 1) * 32 + lg * 8);         \
  } while (0)

  LOADK(kA, 0);

#define STEP(KT, KC, KN) do {                                                \
    const int ktn_ = ((KT) + 1 < 64) ? (KT) + 1 : 63;                        \
    const int m0_ = (KT) * 64;                                               \
    /* V fragments for CURRENT tile: issued early, used after barrier (a) */ \
    bf16x8 vb_[2][4];                                                        \
    _Pragma("unroll")                                                        \
    for (int kk = 0; kk < 2; ++kk)                                           \
      _Pragma("unroll")                                                      \
      for (int cf = 0; cf < 4; ++cf)                                         \
        vb_[kk][cf] = *reinterpret_cast<const bf16x8*>(                      \
            VbT + (size_t)(wave * 64 + cf * 16 + lm) * N_ + m0_ + kk * 32 + lg * 8); \
    LOADK(KN, ktn_);                                                         \
    f32x4 sf[4];                                                             \
    _Pragma("unroll")                                                        \
    for (int kf = 0; kf < 4; ++kf) {                                         \
      sf[kf] = zero4;                                                        \
      sf[kf] = __builtin_amdgcn_mfma_f32_16x16x32_bf16(KC[kf*2], aq[0], sf[kf], 0, 0, 0); \
      sf[kf] = __builtin_amdgcn_mfma_f32_16x16x32_bf16(KC[kf*2+1], aq[1], sf[kf], 0, 0, 0); \
    }                                                                        \
    float v_ = sf[0][0];                                                     \
    _Pragma("unroll")                                                        \
    for (int kf = 0; kf < 4; ++kf)                                           \
      _Pragma("unroll")                                                      \
      for (int r = 0; r < 4; ++r) v_ = fmaxf(v_, sf[kf][r]);                 \
    v_ = fmaxf(v_, __shfl_xor(v_, 16));                                      \
    v_ = fmaxf(v_, __shfl_xor(v_, 32));                                      \
    const bool nres_ = !__all(v_ <= mrow + 8.0f);                            \
    float sc_ = 1.f;                                                         \
    if (nres_) {                                                             \
      float mn_ = fmaxf(mrow, v_);                                           \
      sc_ = exp2f(mrow - mn_);                                               \
      mrow = mn_;                                                            \
    }                                                                        \
    float s_ = 0.f;                                                          \
    _Pragma("unroll")                                                        \
    for (int kf = 0; kf < 4; ++kf)                                           \
      _Pragma("unroll")                                                      \
      for (int r = 0; r < 4; ++r) {                                          \
        float e_ = exp2f(sf[kf][r] - mrow);                                  \
        sf[kf][r] = e_;                                                      \
        s_ += e_;                                                            \
      }                                                                      \
    s_ += __shfl_xor(s_, 16);                                                \
    s_ += __shfl_xor(s_, 32);                                                \
    lrow = lrow * sc_ + s_;                                                  \
    {                                                                        \
      char* prow_ = smem + (wave * 16 + lm) * 128;                           \
      _Pragma("unroll")                                                      \
      for (int kf = 0; kf < 4; ++kf) {                                       \
        uint2 w2_;                                                           \
        w2_.x = cvtpk(sf[kf][0], sf[kf][1]);                                 \
        w2_.y = cvtpk(sf[kf][2], sf[kf][3]);                                 \
        *reinterpret_cast<uint2*>(                                           \
            prow_ + (((kf * 2 + (lg >> 1)) ^ sw) << 4) + ((lg & 1) << 3)) = w2_; \
      }                                                                      \
    }                                                                        \
    if (lg == 0) *(float*)(smem + SCO + (wave * 16 + lm) * 4) = sc_;         \
    if (lane == 0) *(float*)(smem + FLO + wave * 4) = nres_ ? 1.f : 0.f;     \
    __syncthreads();  /* (a): P/SC/FL visible */                             \
    {                                                                        \
      f32x4 fl_ = *reinterpret_cast<const f32x4*>(smem + FLO);               \
      if (fl_[0] + fl_[1] + fl_[2] + fl_[3] > 0.f) {                         \
        _Pragma("unroll")                                                    \
        for (int rb = 0; rb < 4; ++rb) {                                     \
          if (fl_[rb] > 0.f) {                                               \
            f32x4 s4_ = *reinterpret_cast<const f32x4*>(                     \
                smem + SCO + (rb * 16 + lg * 4) * 4);                        \
            _Pragma("unroll")                                                \
            for (int cf = 0; cf < 4; ++cf)                                   \
              _Pragma("unroll")                                              \
              for (int r = 0; r < 4; ++r) accv[rb][cf][r] *= s4_[r];         \
          }                                                                  \
        }                                                                    \
      }                                                                      \
    }                                                                        \
    _Pragma("unroll")                                                        \
    for (int kk = 0; kk < 2; ++kk) {                                         \
      bf16x8 pa_[4];                                                         \
      _Pragma("unroll")                                                      \
      for (int rb = 0; rb < 4; ++rb)                                         \
        pa_[rb] = *reinterpret_cast<const bf16x8*>(                          \
            smem + (rb * 16 + lm) * 128 + (((kk * 4 + lg) ^ sw) << 4));      \
      _Pragma("unroll")                                                      \
      for (int rb = 0; rb < 4; ++rb)                                         \
        _Pragma("unroll")                                                    \
        for (int cf = 0; cf < 4; ++cf)                                       \
          accv[rb][cf] = __builtin_amdgcn_mfma_f32_16x16x32_bf16(            \
              pa_[rb], vb_[kk][cf], accv[rb][cf], 0, 0, 0);                  \
    }                                                                        \
    __syncthreads();  /* (b): P region reusable */                           \
  } while (0)

  for (int kt2 = 0; kt2 < 64; kt2 += 2) {
    STEP(kt2,     kA, kB);
    STEP(kt2 + 1, kB, kA);
  }

  // ---- epilogue ----
  const float g = gamma[0];
  if (lg == 0) *(float*)(smem + SCO + (wave * 16 + lm) * 4) = g / lrow;
  __syncthreads();

  f32x4 il[4];
#pragma unroll
  for (int rb = 0; rb < 4; ++rb)
    il[rb] = *reinterpret_cast<const f32x4*>(smem + SCO + (rb * 16 + lg * 4) * 4);

  float* tlb = (float*)(smem + wave * 8448);  // [64 q][33] f32 per wave
#pragma unroll
  for (int h = 0; h < 2; ++h) {
#pragma unroll
    for (int rb = 0; rb < 4; ++rb)
#pragma unroll
      for (int cfl = 0; cfl < 2; ++cfl) {
        const int cf = h * 2 + cfl;
#pragma unroll
        for (int r = 0; r < 4; ++r)
          tlb[(rb * 16 + lg * 4 + r) * 33 + cfl * 16 + lm] = accv[rb][cf][r] * il[rb][r];
      }
#pragma unroll
    for (int c = 0; c < 32; ++c) {
      float val = tlb[lane * 33 + c];
      size_t gi = ((size_t)(b * C_) + wave * 64 + h * 32 + c) * N_ + q0 + lane;
      out[gi] = val + source[gi];
    }
  }
}

extern "C" void kernel_launch(void* const* d_in, const int* in_sizes, int n_in,
                              void* d_out, int out_size, void* d_ws, size_t ws_size,
                              hipStream_t stream) {
  const float* src = (const float*)d_in[0];
  const float* gui = (const float*)d_in[1];
  const float* Wq  = (const float*)d_in[2];
  const float* Wk  = (const float*)d_in[3];
  const float* Wv  = (const float*)d_in[4];
  const float* bv  = (const float*)d_in[5];
  const float* gm  = (const float*)d_in[6];
  float* out = (float*)d_out;

  u16* Qb = (u16*)d_ws;                         // 4 MB
  u16* Kb = Qb + (size_t)B_ * N_ * CR_;         // 4 MB
  u16* Vb = Kb + (size_t)B_ * N_ * CR_;         // 16 MB (total ws use: 24 MB)

  // scratch inside d_out (33.5 MB): inT 16 MB @0, Wb 288 KB @16 MB
  u16* inT = (u16*)d_out;
  u16* Wb  = inT + (size_t)B_ * N_ * C_;

  wprep_kernel<<<dim3(144), dim3(256), 0, stream>>>(Wq, Wk, Wv, Wb);
  // guidance -> inT, then K and V projections
  transpose_kernel<<<dim3(64, 4, B_), dim3(256), 0, stream>>>(gui, inT);
  projqk_kernel<<<dim3(32, B_), dim3(128), 0, stream>>>(inT, Wb + 64 * 256, Kb);
  projv_kernel<<<dim3(32, B_, 2), dim3(128), 0, stream>>>(inT, Wb + 128 * 256, bv, Vb);
  // source -> inT (reuse), then Q projection
  transpose_kernel<<<dim3(64, 4, B_), dim3(256), 0, stream>>>(src, inT);
  projqk_kernel<<<dim3(32, B_), dim3(128), 0, stream>>>(inT, Wb, Qb);

  attn_kernel<<<dim3(N_ / 64, B_), dim3(256), 0, stream>>>(Qb, Kb, Vb, src, gm, out);
}

// Round 5
// 223.942 us; speedup vs baseline: 1.3041x; 1.3041x over previous
//
#include <hip/hip_runtime.h>
#include <hip/hip_bf16.h>
#include <stdint.h>

// CrossAttention: B=8, C=256, H=W=64 (N=4096), CR=64.
// proj chain (MFMA): wprep -> transpose(gui) -> projK, projV -> transpose(src) -> projQ
//   Qb/Kb stored MFMA-frag-linear: [tile(64px)][frag f<8][lane*8] bf16 (coalesced reads).
// attn: grid (64 qtiles, 2 ch-halves, B), 256 thr = 4 waves, 4 blocks/CU.
//   Wave-local: 16 q x 128 ch per wave; swapped QK^T (D[key][q]) and swapped PV
//   (A=V, B=P -> D[ch][q]); P per-wave in LDS; ONE barrier/iter; V dbuf via gll16.

#define B_ 8
#define C_ 256
#define N_ 4096
#define CR_ 64

typedef unsigned short u16;
typedef __attribute__((ext_vector_type(8))) __bf16 bf16x8;
typedef __attribute__((ext_vector_type(4))) float f32x4;

__device__ __forceinline__ u16 f2bf(float f) {
  union { float f; unsigned int u; } v; v.f = f;
  unsigned int r = (v.u + 0x7fffu + ((v.u >> 16) & 1u)) >> 16;
  return (u16)r;
}
__device__ __forceinline__ unsigned int cvtpk(float a, float b) {
  unsigned int r;
  asm("v_cvt_pk_bf16_f32 %0, %1, %2" : "=v"(r) : "v"(a), "v"(b));
  return r;
}

typedef __attribute__((address_space(1))) const unsigned int gu32_t;
typedef __attribute__((address_space(3))) unsigned int lu32_t;
__device__ __forceinline__ void gll16(const void* g, void* l) {
  __builtin_amdgcn_global_load_lds((gu32_t*)g, (lu32_t*)l, 16, 0, 0);
}

// ---------------- Weight prep ----------------
__global__ __launch_bounds__(256) void wprep_kernel(
    const float* __restrict__ Wq, const float* __restrict__ Wk,
    const float* __restrict__ Wv, u16* __restrict__ Wb)
{
  const int i = (blockIdx.x * 256 + threadIdx.x) * 4;
  const int row = i >> 8;
  float4 v;
  float s = 1.0f;
  if (row < 64)       { v = *(const float4*)(Wq + i); s = 1.44269504f; }
  else if (row < 128) { v = *(const float4*)(Wk + i - 64 * 256); }
  else                { v = *(const float4*)(Wv + i - 128 * 256); }
  u16* o = Wb + i;
  o[0] = f2bf(v.x * s); o[1] = f2bf(v.y * s);
  o[2] = f2bf(v.z * s); o[3] = f2bf(v.w * s);
}

// ---------------- Transpose [C][N] f32 -> [N][C] bf16 ----------------------
__global__ __launch_bounds__(256) void transpose_kernel(
    const float* __restrict__ in, u16* __restrict__ outT)
{
  __shared__ u16 Tl[64 * 66];
  const int t = threadIdx.x;
  const int px0 = blockIdx.x * 64, ch0 = blockIdx.y * 64, b = blockIdx.z;
  const float* ip = in + ((size_t)(b * C_ + ch0)) * N_ + px0;
  const int cx = t >> 4, p4 = (t & 15) * 4;
#pragma unroll
  for (int p = 0; p < 4; ++p) {
    const int ch = cx + p * 16;
    float4 v = *(const float4*)(ip + (size_t)ch * N_ + p4);
    Tl[(p4 + 0) * 66 + ch] = f2bf(v.x);
    Tl[(p4 + 1) * 66 + ch] = f2bf(v.y);
    Tl[(p4 + 2) * 66 + ch] = f2bf(v.z);
    Tl[(p4 + 3) * 66 + ch] = f2bf(v.w);
  }
  __syncthreads();
  const int row = t >> 3, seg = t & 7;
  u16* op = outT + ((size_t)(b * N_) + px0) * C_ + ch0 + seg * 8;
#pragma unroll
  for (int p = 0; p < 2; ++p) {
    const int r2 = row + p * 32;
    *(uint4*)(op + (size_t)r2 * C_) = *(const uint4*)(&Tl[r2 * 66 + seg * 8]);
  }
}

// ---------------- Q/K projection (MFMA), frag-linear output ----------------
// grid (32 px-blocks, B), 128 thr = 2 waves; wave tile = 64 px x 64 ch.
// Output: dst[tile tt][frag f][lane] with tt = b*64 + bx*2 + wave,
//   frag f holds rows (f>>1)*16+lm (px), k-cols (f&1)*32+lg*8 (ch).
__global__ __launch_bounds__(128) void projqk_kernel(
    const u16* __restrict__ inT, const u16* __restrict__ W64, u16* __restrict__ dst)
{
  __shared__ u16 Tl[2 * 64 * 72];
  const int t = threadIdx.x, lane = t & 63, wave = t >> 6;
  const int lg = lane >> 4, lm = lane & 15;
  const int b = blockIdx.y;
  const int px0 = blockIdx.x * 128 + wave * 64;
  const u16* ib = inT + ((size_t)(b * N_) + px0) * C_;

  f32x4 acc[4][4];
  const f32x4 z4 = {0.f, 0.f, 0.f, 0.f};
#pragma unroll
  for (int i = 0; i < 4; ++i)
#pragma unroll
    for (int j = 0; j < 4; ++j) acc[i][j] = z4;

  for (int ks = 0; ks < 8; ++ks) {
    bf16x8 wf[4], pf[4];
#pragma unroll
    for (int mi = 0; mi < 4; ++mi)
      wf[mi] = *(const bf16x8*)(W64 + (mi * 16 + lm) * C_ + ks * 32 + lg * 8);
#pragma unroll
    for (int ni = 0; ni < 4; ++ni)
      pf[ni] = *(const bf16x8*)(ib + (size_t)(ni * 16 + lm) * C_ + ks * 32 + lg * 8);
#pragma unroll
    for (int mi = 0; mi < 4; ++mi)
#pragma unroll
      for (int ni = 0; ni < 4; ++ni)
        acc[mi][ni] = __builtin_amdgcn_mfma_f32_16x16x32_bf16(wf[mi], pf[ni], acc[mi][ni], 0, 0, 0);
  }

  // D[ch][px] -> Tl[px][ch] (stride 72 for 16B-aligned b128 reads)
  u16* tw = Tl + wave * 64 * 72;
#pragma unroll
  for (int mi = 0; mi < 4; ++mi)
#pragma unroll
    for (int ni = 0; ni < 4; ++ni)
#pragma unroll
      for (int rp = 0; rp < 2; ++rp)
        *(unsigned int*)&tw[(ni * 16 + lm) * 72 + mi * 16 + lg * 4 + rp * 2] =
            cvtpk(acc[mi][ni][rp * 2], acc[mi][ni][rp * 2 + 1]);

  const int tt = b * 64 + blockIdx.x * 2 + wave;
  u16* op = dst + (size_t)tt * 4096 + lane * 8;
#pragma unroll
  for (int f = 0; f < 8; ++f)
    *(uint4*)(op + f * 512) =
        *(const uint4*)(&Tl[(wave * 64 + (f >> 1) * 16 + lm) * 72 + (f & 1) * 32 + lg * 8]);
}

// ---------------- V projection (MFMA) -> Vb [ch][n] ------------------------
__global__ __launch_bounds__(128) void projv_kernel(
    const u16* __restrict__ inT, const u16* __restrict__ Wv256,
    const float* __restrict__ bv, u16* __restrict__ Vb)
{
  const int t = threadIdx.x, lane = t & 63, wave = t >> 6;
  const int lg = lane >> 4, lm = lane & 15;
  const int b = blockIdx.y;
  const int px0 = blockIdx.x * 128;
  const int chb = blockIdx.z * 128 + wave * 64;
  const u16* ib = inT + ((size_t)(b * N_) + px0) * C_;
  const u16* wb = Wv256 + (size_t)chb * C_;

  f32x4 bq[4];
#pragma unroll
  for (int mi = 0; mi < 4; ++mi)
    bq[mi] = *(const f32x4*)(bv + chb + mi * 16 + lg * 4);

  const f32x4 z4 = {0.f, 0.f, 0.f, 0.f};
  for (int pg = 0; pg < 2; ++pg) {
    f32x4 acc[4][4];
#pragma unroll
    for (int i = 0; i < 4; ++i)
#pragma unroll
      for (int j = 0; j < 4; ++j) acc[i][j] = z4;
    for (int ks = 0; ks < 8; ++ks) {
      bf16x8 wf[4], pf[4];
#pragma unroll
      for (int mi = 0; mi < 4; ++mi)
        wf[mi] = *(const bf16x8*)(wb + (mi * 16 + lm) * C_ + ks * 32 + lg * 8);
#pragma unroll
      for (int ni = 0; ni < 4; ++ni)
        pf[ni] = *(const bf16x8*)(ib + (size_t)(pg * 64 + ni * 16 + lm) * C_ + ks * 32 + lg * 8);
#pragma unroll
      for (int mi = 0; mi < 4; ++mi)
#pragma unroll
        for (int ni = 0; ni < 4; ++ni)
          acc[mi][ni] = __builtin_amdgcn_mfma_f32_16x16x32_bf16(wf[mi], pf[ni], acc[mi][ni], 0, 0, 0);
    }
#pragma unroll
    for (int mi = 0; mi < 4; ++mi)
#pragma unroll
      for (int ni = 0; ni < 4; ++ni)
#pragma unroll
        for (int r = 0; r < 4; ++r)
          Vb[((size_t)(b * C_) + chb + mi * 16 + lg * 4 + r) * N_ +
             px0 + pg * 64 + ni * 16 + lm] = f2bf(acc[mi][ni][r] + bq[mi][r]);
  }
}

// ---------------- Flash attention ----------------
// LDS: Vbuf0 [0,16384), Vbuf1 [16384,32768), P [32768,40960): 4 waves x 16q x 128B.
#define VB1 16384
#define PB  32768

__global__ __launch_bounds__(256, 4) void attn_kernel(
    const u16* __restrict__ Qb, const u16* __restrict__ Kb, const u16* __restrict__ Vb,
    const float* __restrict__ source, const float* __restrict__ gamma,
    float* __restrict__ out)
{
  __shared__ uint4 smem4[2560];  // 40960 B
  char* smem = (char*)smem4;

  const int t = threadIdx.x;
  const int lane = t & 63;
  const int wave = t >> 6;
  const int lg = lane >> 4;
  const int lm = lane & 15;
  const int b = blockIdx.z;
  const int half = blockIdx.y;
  const int q0 = blockIdx.x * 64;
  const int sw = lm & 7;

  // Q fragments (B-operand: col=q=lm, k=lg*8+j), frag-linear layout
  bf16x8 aq[2];
  {
    const u16* qp = Qb + (((size_t)(b * 64 + blockIdx.x) * 8 + wave * 2) * 512) + lane * 8;
    aq[0] = *(const bf16x8*)qp;
    aq[1] = *(const bf16x8*)(qp + 512);
  }

  const u16* KbT = Kb + (size_t)b * N_ * CR_;
  const char* VbB = (const char*)(Vb + ((size_t)(b * C_) + half * 128) * N_);

  // V staging: 4 gll16/thread, pre-swizzled global source, linear LDS dest
  const int srow = t >> 3, cslot = t & 7;
  unsigned int vgo[4];
#pragma unroll
  for (int i = 0; i < 4; ++i) {
    int row = i * 32 + srow;
    int cl = cslot ^ (row & 7);
    vgo[i] = (unsigned int)((row * N_ + cl * 8) * 2);
  }

  f32x4 accv[8];
  const f32x4 zero4 = {0.f, 0.f, 0.f, 0.f};
#pragma unroll
  for (int i = 0; i < 8; ++i) accv[i] = zero4;
  float mrow = -1e30f, lrow = 0.f;

  bf16x8 kC[8];
  char* pslice = smem + PB + wave * 2048 + lm * 128;

#define STAGEV(KTILE, VOFF) do {                                             \
    unsigned int vadd_ = (unsigned int)((KTILE) * 128);                      \
    _Pragma("unroll")                                                        \
    for (int i = 0; i < 4; ++i)                                              \
      gll16(VbB + vgo[i] + vadd_, smem + (VOFF) + i * 4096 + wave * 1024);   \
  } while (0)

#define LOADK(KT) do {                                                       \
    const u16* kb_ = KbT + (size_t)(KT) * 4096 + lane * 8;                   \
    _Pragma("unroll")                                                        \
    for (int f = 0; f < 8; ++f)                                              \
      kC[f] = *(const bf16x8*)(kb_ + f * 512);                               \
  } while (0)

#define ITER(KT, VCUR, VNXT) do {                                            \
    __syncthreads();  /* V(KT) staged+drained; V(VNXT) free */               \
    LOADK(KT);                                                               \
    const int ktn_ = ((KT) + 1 < 64) ? (KT) + 1 : 63;                        \
    STAGEV(ktn_, VNXT);                                                      \
    /* S^T: D[key=kf*16+lg*4+r][q=lm] */                                     \
    f32x4 sf[4];                                                             \
    __builtin_amdgcn_s_setprio(1);                                           \
    _Pragma("unroll")                                                        \
    for (int kf = 0; kf < 4; ++kf) {                                         \
      sf[kf] = zero4;                                                        \
      sf[kf] = __builtin_amdgcn_mfma_f32_16x16x32_bf16(kC[kf*2], aq[0], sf[kf], 0, 0, 0); \
      sf[kf] = __builtin_amdgcn_mfma_f32_16x16x32_bf16(kC[kf*2+1], aq[1], sf[kf], 0, 0, 0); \
    }                                                                        \
    __builtin_amdgcn_s_setprio(0);                                           \
    float v_ = sf[0][0];                                                     \
    _Pragma("unroll")                                                        \
    for (int kf = 0; kf < 4; ++kf)                                           \
      _Pragma("unroll")                                                      \
      for (int r = 0; r < 4; ++r) v_ = fmaxf(v_, sf[kf][r]);                 \
    v_ = fmaxf(v_, __shfl_xor(v_, 16));                                      \
    v_ = fmaxf(v_, __shfl_xor(v_, 32));                                      \
    if (!__all(v_ <= mrow + 8.0f)) {                                         \
      float mn_ = fmaxf(mrow, v_);                                           \
      float sc_ = exp2f(mrow - mn_);                                         \
      mrow = mn_;                                                            \
      lrow *= sc_;                                                           \
      _Pragma("unroll")                                                      \
      for (int cf = 0; cf < 8; ++cf)                                         \
        _Pragma("unroll")                                                    \
        for (int r = 0; r < 4; ++r) accv[cf][r] *= sc_;                      \
    }                                                                        \
    float s_ = 0.f;                                                          \
    _Pragma("unroll")                                                        \
    for (int kf = 0; kf < 4; ++kf)                                           \
      _Pragma("unroll")                                                      \
      for (int r = 0; r < 4; ++r) {                                          \
        float e_ = exp2f(sf[kf][r] - mrow);                                  \
        sf[kf][r] = e_;                                                      \
        s_ += e_;                                                            \
      }                                                                      \
    s_ += __shfl_xor(s_, 16);                                                \
    s_ += __shfl_xor(s_, 32);                                                \
    lrow += s_;                                                              \
    /* P write: row q=lm (wave-local), chunk-XOR swizzle */                  \
    _Pragma("unroll")                                                        \
    for (int kf = 0; kf < 4; ++kf) {                                         \
      uint2 w2_;                                                             \
      w2_.x = cvtpk(sf[kf][0], sf[kf][1]);                                   \
      w2_.y = cvtpk(sf[kf][2], sf[kf][3]);                                   \
      *reinterpret_cast<uint2*>(                                             \
          pslice + (((kf * 2 + (lg >> 1)) ^ sw) << 4) + ((lg & 1) << 3)) = w2_; \
    }                                                                        \
    /* PV swapped: A=V[ch][k], B=P[q=lm][k] -> D[ch=cf*16+lg*4+r][q=lm] */   \
    _Pragma("unroll")                                                        \
    for (int kk = 0; kk < 2; ++kk) {                                         \
      bf16x8 pb_ = *reinterpret_cast<const bf16x8*>(                         \
          pslice + (((kk * 4 + lg) ^ sw) << 4));                             \
      __builtin_amdgcn_s_setprio(1);                                         \
      _Pragma("unroll")                                                      \
      for (int cf = 0; cf < 8; ++cf) {                                       \
        bf16x8 vf_ = *reinterpret_cast<const bf16x8*>(                       \
            smem + (VCUR) + (cf * 16 + lm) * 128 + (((kk * 4 + lg) ^ sw) << 4)); \
        accv[cf] = __builtin_amdgcn_mfma_f32_16x16x32_bf16(vf_, pb_, accv[cf], 0, 0, 0); \
      }                                                                      \
      __builtin_amdgcn_s_setprio(0);                                         \
    }                                                                        \
  } while (0)

  STAGEV(0, 0);
  for (int kt2 = 0; kt2 < 64; kt2 += 2) {
    ITER(kt2,     0,   VB1);
    ITER(kt2 + 1, VB1, 0);
  }

  // ---- epilogue: out[b][ch][q0+wave*16+lm] = accv*inv + source ----
  const float inv = gamma[0] / lrow;
#pragma unroll
  for (int cf = 0; cf < 8; ++cf)
#pragma unroll
    for (int r = 0; r < 4; ++r) {
      const int ch = half * 128 + cf * 16 + lg * 4 + r;
      size_t gi = ((size_t)(b * C_ + ch)) * N_ + q0 + wave * 16 + lm;
      out[gi] = accv[cf][r] * inv + source[gi];
    }
}

extern "C" void kernel_launch(void* const* d_in, const int* in_sizes, int n_in,
                              void* d_out, int out_size, void* d_ws, size_t ws_size,
                              hipStream_t stream) {
  const float* src = (const float*)d_in[0];
  const float* gui = (const float*)d_in[1];
  const float* Wq  = (const float*)d_in[2];
  const float* Wk  = (const float*)d_in[3];
  const float* Wv  = (const float*)d_in[4];
  const float* bv  = (const float*)d_in[5];
  const float* gm  = (const float*)d_in[6];
  float* out = (float*)d_out;

  u16* Qb = (u16*)d_ws;                         // 4 MB
  u16* Kb = Qb + (size_t)B_ * N_ * CR_;         // 4 MB
  u16* Vb = Kb + (size_t)B_ * N_ * CR_;         // 16 MB (ws total 24 MB)

  // scratch inside d_out (32 MB): inT 16 MB @0, Wb 288 KB @16 MB
  u16* inT = (u16*)d_out;
  u16* Wb  = inT + (size_t)B_ * N_ * C_;

  wprep_kernel<<<dim3(144), dim3(256), 0, stream>>>(Wq, Wk, Wv, Wb);
  transpose_kernel<<<dim3(64, 4, B_), dim3(256), 0, stream>>>(gui, inT);
  projqk_kernel<<<dim3(32, B_), dim3(128), 0, stream>>>(inT, Wb + 64 * 256, Kb);
  projv_kernel<<<dim3(32, B_, 2), dim3(128), 0, stream>>>(inT, Wb + 128 * 256, bv, Vb);
  transpose_kernel<<<dim3(64, 4, B_), dim3(256), 0, stream>>>(src, inT);
  projqk_kernel<<<dim3(32, B_), dim3(128), 0, stream>>>(inT, Wb, Qb);

  attn_kernel<<<dim3(64, 2, B_), dim3(256), 0, stream>>>(Qb, Kb, Vb, src, gm, out);
}